// Round 1
// baseline (346.374 us; speedup 1.0000x reference)
//
#include <hip/hip_runtime.h>

// T1: (P=4, B=8192, C=128, 3, 3) fp32
// T2: (1, B, C, 3, 3) fp32 (broadcast over P)
// out[p,b,c,i,j] = sum_k T1[p,b,c,i,k] * T2[0,b,c,k,j]
//
// Each thread handles 4 consecutive (b,c) cells -> 36 consecutive floats
// (9 float4) per tensor per p. Fully vectorized dwordx4 loads/stores.

__global__ __launch_bounds__(256) void tc33_kernel(const float* __restrict__ T1,
                                                   const float* __restrict__ T2,
                                                   float* __restrict__ out) {
    const long long PER_P = 9LL * 8192 * 128;      // floats per p-slice (9,437,184)
    long long t = (long long)blockIdx.x * blockDim.x + threadIdx.x;  // 0..262143
    long long base = t * 36;                        // float offset of first cell

    // Load B (T2) once: 9 float4 = 36 floats = 4 cells' worth of 3x3 matrices
    float b[36];
    {
        const float4* B4 = reinterpret_cast<const float4*>(T2 + base);
        #pragma unroll
        for (int j = 0; j < 9; ++j) {
            float4 v = B4[j];
            b[4*j+0] = v.x; b[4*j+1] = v.y; b[4*j+2] = v.z; b[4*j+3] = v.w;
        }
    }

    #pragma unroll
    for (int p = 0; p < 4; ++p) {
        float a[36];
        {
            const float4* A4 = reinterpret_cast<const float4*>(T1 + p * PER_P + base);
            #pragma unroll
            for (int j = 0; j < 9; ++j) {
                float4 v = A4[j];
                a[4*j+0] = v.x; a[4*j+1] = v.y; a[4*j+2] = v.z; a[4*j+3] = v.w;
            }
        }
        float o[36];
        #pragma unroll
        for (int u = 0; u < 4; ++u) {          // 4 cells per thread
            #pragma unroll
            for (int i = 0; i < 3; ++i) {
                #pragma unroll
                for (int j = 0; j < 3; ++j) {
                    float s = a[u*9 + i*3 + 0] * b[u*9 + 0*3 + j];
                    s = fmaf(a[u*9 + i*3 + 1], b[u*9 + 1*3 + j], s);
                    s = fmaf(a[u*9 + i*3 + 2], b[u*9 + 2*3 + j], s);
                    o[u*9 + i*3 + j] = s;
                }
            }
        }
        float4* O4 = reinterpret_cast<float4*>(out + p * PER_P + base);
        #pragma unroll
        for (int j = 0; j < 9; ++j) {
            float4 v;
            v.x = o[4*j+0]; v.y = o[4*j+1]; v.z = o[4*j+2]; v.w = o[4*j+3];
            O4[j] = v;
        }
    }
}

extern "C" void kernel_launch(void* const* d_in, const int* in_sizes, int n_in,
                              void* d_out, int out_size, void* d_ws, size_t ws_size,
                              hipStream_t stream) {
    const float* T1 = (const float*)d_in[0];
    const float* T2 = (const float*)d_in[1];
    float* out = (float*)d_out;

    // cells = B*C = 1,048,576; 4 cells/thread -> 262,144 threads -> 1024 blocks
    const int threads = 256;
    const int blocks = (8192 * 128 / 4) / threads;  // 1024
    tc33_kernel<<<blocks, threads, 0, stream>>>(T1, T2, out);
}

// Round 3
// 286.307 us; speedup vs baseline: 1.2098x; 1.2098x over previous
//
#include <hip/hip_runtime.h>

// T1: (P=4, B=8192, C=128, 3, 3) fp32
// T2: (1, B, C, 3, 3) fp32 (broadcast over P)
// out[p,b,c,i,j] = sum_k T1[p,b,c,i,k] * T2[0,b,c,k,j]
//
// R1 showed WRITE_SIZE = 1.92x output bytes from lane-strided 144B-chunk
// float4 stores (partial-line HBM write amplification). Loads were fine
// (FETCH ~= T1 only; T2 L3-resident). This version keeps the strided
// vectorized loads but routes stores through LDS so global stores are
// lane-contiguous full-line writes, marked nontemporal.
// (R2 fix: __builtin_nontemporal_store needs a clang ext_vector type,
// not HIP's float4 class.)

typedef float floatx4 __attribute__((ext_vector_type(4)));

__global__ __launch_bounds__(256) void tc33_kernel(const float* __restrict__ T1,
                                                   const float* __restrict__ T2,
                                                   float* __restrict__ out) {
    __shared__ float so[9216];                     // 36 KB: one p-slice chunk of out
    const long long PER_P = 9LL * 8192 * 128;      // floats per p-slice (9,437,184)
    const int tid = threadIdx.x;
    const long long blockBase = (long long)blockIdx.x * 9216;  // floats
    const long long base = blockBase + tid * 36;   // this thread's 4 cells

    // Load B (T2) once: 9 float4 = 36 floats = 4 cells' worth of 3x3 matrices
    float b[36];
    {
        const float4* B4 = reinterpret_cast<const float4*>(T2 + base);
        #pragma unroll
        for (int j = 0; j < 9; ++j) {
            float4 v = B4[j];
            b[4*j+0] = v.x; b[4*j+1] = v.y; b[4*j+2] = v.z; b[4*j+3] = v.w;
        }
    }

    #pragma unroll
    for (int p = 0; p < 4; ++p) {
        float a[36];
        {
            const float4* A4 = reinterpret_cast<const float4*>(T1 + p * PER_P + base);
            #pragma unroll
            for (int j = 0; j < 9; ++j) {
                float4 v = A4[j];
                a[4*j+0] = v.x; a[4*j+1] = v.y; a[4*j+2] = v.z; a[4*j+3] = v.w;
            }
        }

        float o[36];
        #pragma unroll
        for (int u = 0; u < 4; ++u) {          // 4 cells per thread
            #pragma unroll
            for (int i = 0; i < 3; ++i) {
                #pragma unroll
                for (int j = 0; j < 3; ++j) {
                    float s = a[u*9 + i*3 + 0] * b[u*9 + 0*3 + j];
                    s = fmaf(a[u*9 + i*3 + 1], b[u*9 + 1*3 + j], s);
                    s = fmaf(a[u*9 + i*3 + 2], b[u*9 + 2*3 + j], s);
                    o[u*9 + i*3 + j] = s;
                }
            }
        }

        if (p) __syncthreads();                // protect LDS reuse from prev p
        // Thread-local layout into LDS (matches global layout of this block's chunk)
        {
            floatx4* S4w = reinterpret_cast<floatx4*>(&so[tid * 36]);
            #pragma unroll
            for (int j = 0; j < 9; ++j) {
                floatx4 v;
                v.x = o[4*j+0]; v.y = o[4*j+1]; v.z = o[4*j+2]; v.w = o[4*j+3];
                S4w[j] = v;
            }
        }
        __syncthreads();

        // Cooperative fully-coalesced store: 2304 float4, lane-contiguous
        {
            const floatx4* S4 = reinterpret_cast<const floatx4*>(so);
            floatx4* O4 = reinterpret_cast<floatx4*>(out + p * PER_P + blockBase);
            #pragma unroll
            for (int j = 0; j < 9; ++j) {
                floatx4 v = S4[tid + 256 * j];
                __builtin_nontemporal_store(v, &O4[tid + 256 * j]);
            }
        }
    }
}

extern "C" void kernel_launch(void* const* d_in, const int* in_sizes, int n_in,
                              void* d_out, int out_size, void* d_ws, size_t ws_size,
                              hipStream_t stream) {
    const float* T1 = (const float*)d_in[0];
    const float* T2 = (const float*)d_in[1];
    float* out = (float*)d_out;

    // cells = B*C = 1,048,576; 4 cells/thread -> 262,144 threads -> 1024 blocks
    const int threads = 256;
    const int blocks = (8192 * 128 / 4) / threads;  // 1024
    tc33_kernel<<<blocks, threads, 0, stream>>>(T1, T2, out);
}